// Round 1
// baseline (776.913 us; speedup 1.0000x reference)
//
#include <hip/hip_runtime.h>

// Problem constants (fixed by the reference):
//   B=4096 tokens, K=8 experts/token, H=4096 hidden, E=64 experts, N=B*K=32768
#define B_TOK 4096
#define K_EXP 8
#define H_DIM 4096
#define E_NUM 64
#define N_SLOT (B_TOK * K_EXP)       // 32768
#define NBLK 64                      // histogram/rank blocks
#define CHUNK 512                    // N_SLOT / NBLK

// ---------------------------------------------------------------------------
// Kernel 1: per-block expert histogram. part[blk][e] = #slots in chunk blk
// with expert e.  64 blocks x 512 threads, LDS atomics.
// ---------------------------------------------------------------------------
__global__ void hist_kernel(const int* __restrict__ eids, int* __restrict__ part) {
    __shared__ int cnt[E_NUM];
    const int tid = threadIdx.x;
    if (tid < E_NUM) cnt[tid] = 0;
    __syncthreads();
    const int i = blockIdx.x * CHUNK + tid;
    const int e = eids[i];
    atomicAdd(&cnt[e], 1);
    __syncthreads();
    if (tid < E_NUM) part[blockIdx.x * E_NUM + tid] = cnt[tid];
}

// ---------------------------------------------------------------------------
// Kernel 2: exclusive scan over (expert, block).
// offs[blk][e] = (#slots with expert < e anywhere) + (#slots with expert e in
// chunks < blk).  One wave (64 threads), thread e owns expert e.
// ---------------------------------------------------------------------------
__global__ void scan_kernel(const int* __restrict__ part, int* __restrict__ offs) {
    __shared__ int totals[E_NUM];
    const int e = threadIdx.x;          // 64 threads = 1 wave
    int tot = 0;
    for (int b = 0; b < NBLK; ++b) tot += part[b * E_NUM + e];
    totals[e] = tot;
    __syncthreads();
    int base = 0;
    for (int ee = 0; ee < e; ++ee) base += totals[ee];
    int run = base;
    for (int b = 0; b < NBLK; ++b) {
        offs[b * E_NUM + e] = run;
        run += part[b * E_NUM + e];
    }
}

// ---------------------------------------------------------------------------
// Kernel 3: stable rank within chunk -> inv[i] (position of slot i in the
// stable-sorted order).  64 blocks x 512 threads; O(tid) LDS byte scan.
// ---------------------------------------------------------------------------
__global__ void inv_kernel(const int* __restrict__ eids, const int* __restrict__ offs,
                           int* __restrict__ inv) {
    __shared__ unsigned char ids[CHUNK];
    const int tid = threadIdx.x;
    const int i = blockIdx.x * CHUNK + tid;
    const int e = eids[i];
    ids[tid] = (unsigned char)e;
    __syncthreads();
    int rank = 0;
    for (int j = 0; j < tid; ++j) rank += (ids[j] == (unsigned char)e) ? 1 : 0;
    inv[i] = offs[blockIdx.x * E_NUM + e] + rank;
}

// ---------------------------------------------------------------------------
// Kernel 4: combine.  out[b,h] = sum_k scales[b,k] * expand_x[inv[b*K+k], h],
// written to both output copies.  One block per token, float4 vectorized.
// Each expand_x row is read exactly once across the grid (inv is a perm).
// ---------------------------------------------------------------------------
__global__ __launch_bounds__(256) void combine_kernel(
        const float* __restrict__ scales,
        const float* __restrict__ ex,
        const int* __restrict__ inv,
        float* __restrict__ out0,
        float* __restrict__ out1) {
    const int b = blockIdx.x;
    __shared__ int   rows[K_EXP];
    __shared__ float ss[K_EXP];
    const int tid = threadIdx.x;
    if (tid < K_EXP) {
        rows[tid] = inv[b * K_EXP + tid];
        ss[tid]   = scales[b * K_EXP + tid];
    }
    __syncthreads();

    const float4* ex4 = (const float4*)ex;
    float4* o0 = (float4*)(out0 + (size_t)b * H_DIM);
    float4* o1 = (float4*)(out1 + (size_t)b * H_DIM);
    const int H4 = H_DIM / 4;           // 1024 float4 per row

    // hoist row bases + scales into registers
    size_t rbase[K_EXP];
    float  sreg[K_EXP];
#pragma unroll
    for (int k = 0; k < K_EXP; ++k) {
        rbase[k] = (size_t)rows[k] * H4;
        sreg[k]  = ss[k];
    }

#pragma unroll
    for (int it = 0; it < 4; ++it) {     // H4 / 256
        const int c = tid + it * 256;
        float4 acc = make_float4(0.f, 0.f, 0.f, 0.f);
#pragma unroll
        for (int k = 0; k < K_EXP; ++k) {
            const float4 v = ex4[rbase[k] + c];
            const float s = sreg[k];
            acc.x += s * v.x; acc.y += s * v.y;
            acc.z += s * v.z; acc.w += s * v.w;
        }
        o0[c] = acc;
        o1[c] = acc;
    }
}

// ---------------------------------------------------------------------------
// Inputs (setup_inputs order):
//   d_in[0] x              (B,H)  f32   -- unused (golden override)
//   d_in[1] expert_ids     (B,K)  i32
//   d_in[2] expert_scales  (B,K)  f32
//   d_in[3] golden_expand_x(B*K,H)f32
//   d_in[4] moe_expert_num scalar i32   -- fixed 64
// Output: (out, out) concatenated -> 2*B*H f32.
// ---------------------------------------------------------------------------
extern "C" void kernel_launch(void* const* d_in, const int* in_sizes, int n_in,
                              void* d_out, int out_size, void* d_ws, size_t ws_size,
                              hipStream_t stream) {
    const int*   eids   = (const int*)d_in[1];
    const float* scales = (const float*)d_in[2];
    const float* ex     = (const float*)d_in[3];
    float* out0 = (float*)d_out;
    float* out1 = (float*)d_out + (size_t)B_TOK * H_DIM;

    int* ws   = (int*)d_ws;
    int* part = ws;                         // [64][64]
    int* offs = ws + NBLK * E_NUM;          // [64][64]
    int* inv  = ws + 2 * NBLK * E_NUM;      // [32768]

    hist_kernel<<<NBLK, CHUNK, 0, stream>>>(eids, part);
    scan_kernel<<<1, E_NUM, 0, stream>>>(part, offs);
    inv_kernel<<<NBLK, CHUNK, 0, stream>>>(eids, offs, inv);
    combine_kernel<<<B_TOK, 256, 0, stream>>>(scales, ex, inv, out0, out1);
}